// Round 8
// baseline (242.397 us; speedup 1.0000x reference)
//
#include <hip/hip_runtime.h>
#include <hip/hip_bf16.h>

// DIM=768, H=4, D_H=192, R_H=4, N_EXP=6, TOPK=3, BETA=0.5, BATCH=65536
// Routing is batch-independent. Fold softmax/topk/renorm/BETA into c[h][e],
// then precompute the DENSE per-head matrix, stored transposed in bf16:
//   Wt[h][n][k] = sum_s c[h][s/4] * A[s/4][k][s%4] * B[s/4][s%4][n]
// (295 KB -> L2-resident). Main op: out = z + z @ W[h] per head.
//
// v8: same transposed-MFMA math as v7 (A-operand = Wt[n][k], B-operand = z^T,
// D per lane = 4 consecutive n -> f32x4 residual-init & store), but executed
// as 256-THREAD BLOCKS (4 waves x 16 rows, one head per block):
//  - per-wave live state ~55-60 VGPR (acc[6]+bfrag+afrag) — the envelope the
//    allocator provably honors for 256-thd blocks (r3: 60 VGPR, no spill).
//    r7's 1-wave blocks hit the 16-wg/CU occupancy cap (45%) AND spilled
//    (VGPR=48 < live demand -> +70MB fetch / +39MB write scratch traffic).
//  - occupancy cap 32 waves/CU (threads-limited), 2x r7.
//  - Wt fragments: per-kb working set 1.5 KB, L1-resident, shared by 4 waves.
//  - plain stores (not NT) so L2 merges 64B/row partials into full lines
//    (r7 NT stores showed 1.2x write amplification).
// mfma_f32_16x16x32_bf16 layouts (m89-verified):
//   A: row=l&15, k=(l>>4)*8+j   B: col=l&15, same k   C/D: col=l&15, row=(l>>4)*4+r

typedef short bf16x8 __attribute__((ext_vector_type(8)));
typedef float f32x4 __attribute__((ext_vector_type(4)));
typedef unsigned int u32;

__global__ void dff_setup(const float* __restrict__ A,
                          const float* __restrict__ Bm,
                          const float* __restrict__ Zs,
                          const float* __restrict__ Za,
                          __hip_bfloat16* __restrict__ Wt) {
  __shared__ float c[4][6];
  const int t = threadIdx.x;
  if (t < 4) {
    const int h = t;
    float cc[6] = {0.f, 0.f, 0.f, 0.f, 0.f, 0.f};
    for (int rt = 0; rt < 2; ++rt) {
      const float* Z = rt ? Za : Zs;
      float zz[6];
      float mx = -1e30f;
      for (int e = 0; e < 6; ++e) { zz[e] = Z[h * 6 + e]; mx = fmaxf(mx, zz[e]); }
      float p[6];
      float sum = 0.f;
      for (int e = 0; e < 6; ++e) { p[e] = expf(zz[e] - mx); sum += p[e]; }
      for (int e = 0; e < 6; ++e) p[e] /= sum;
      // top-3 (ties -> lowest index, matching lax.top_k)
      bool used[6] = {false, false, false, false, false, false};
      float ws = 0.f;
      int sel[3];
      float pv[3];
      for (int k = 0; k < 3; ++k) {
        int best = -1;
        float bv = -1.f;
        for (int e = 0; e < 6; ++e)
          if (!used[e] && p[e] > bv) { bv = p[e]; best = e; }
        used[best] = true;
        sel[k] = best;
        pv[k] = bv;
        ws += bv;
      }
      const float inv = 1.f / (ws + 1e-8f);
      for (int k = 0; k < 3; ++k) cc[sel[k]] += pv[k] * inv;
    }
    for (int e = 0; e < 6; ++e) c[h][e] = 0.5f * cc[e];  // BETA folded in
  }
  __syncthreads();
  // Wt[h][n][k] = sum_s c[h][e]*A[e*768 + k*4 + r]*Bm[s*192 + n],  s=e*4+r
  for (int idx = blockIdx.x * blockDim.x + threadIdx.x; idx < 4 * 192 * 192;
       idx += gridDim.x * blockDim.x) {
    const int h = idx / (192 * 192);
    const int rem = idx % (192 * 192);
    const int n = rem / 192;
    const int k = rem % 192;
    float acc = 0.f;
#pragma unroll
    for (int s = 0; s < 24; ++s) {
      const int e = s >> 2, r = s & 3;
      acc += c[h][e] * A[e * 768 + k * 4 + r] * Bm[s * 192 + n];
    }
    Wt[idx] = __float2bfloat16(acc);
  }
}

// f32 -> bf16 (round half up via +0x8000) packed pair into one u32.
__device__ __forceinline__ u32 pack_bf16(float a, float b) {
  const u32 ua = __builtin_bit_cast(u32, a) + 0x8000u;
  const u32 ub = __builtin_bit_cast(u32, b) + 0x8000u;
  return (ua >> 16) | (ub & 0xFFFF0000u);
}

__global__ __launch_bounds__(256, 4)
void dff_mfma(const float* __restrict__ z,
              const __hip_bfloat16* __restrict__ Wt,
              float* __restrict__ out) {
  const int t = threadIdx.x;        // 0..255
  const int l = t & 63;             // lane
  const int w = t >> 6;             // wave 0..3
  const int lr = l & 15;
  const int lg = l >> 4;            // 0..3
  const int h = blockIdx.y;         // head (block-uniform)
  const size_t row0 = (size_t)blockIdx.x * 64 + w * 16;  // 16 rows per wave
  const float* __restrict__ zb = z + row0 * 768 + h * 192;
  float* __restrict__ ob = out + row0 * 768 + h * 192;
  const short* __restrict__ Wh =
      reinterpret_cast<const short*>(Wt) + h * (192 * 192);

  // Two halves of the n-range (6 tiles each) to bound live registers.
#pragma unroll 1
  for (int nh = 0; nh < 2; ++nh) {
    const int n0 = nh * 96;

    // acc[i]: D tile (n-tile n0/16+i). Residual init: f32x4 at out-position —
    // row lr, cols n0 + i*16 + lg*4 .. +3.
    f32x4 acc[6];
#pragma unroll
    for (int i = 0; i < 6; ++i)
      acc[i] = *reinterpret_cast<const f32x4*>(
          zb + (size_t)lr * 768 + n0 + i * 16 + lg * 4);

#pragma unroll 1
    for (int kb = 0; kb < 6; ++kb) {
      // B fragment (z^T): col = batch row lr, k = kb*32 + lg*8 + j.
      // Wave footprint 16 rows x 128B contiguous — coalesced, L1/L2-hot.
      const float* p = zb + (size_t)lr * 768 + kb * 32 + lg * 8;
      const f32x4 x0 = *reinterpret_cast<const f32x4*>(p);
      const f32x4 x1 = *reinterpret_cast<const f32x4*>(p + 4);
      u32 wd[4];
      wd[0] = pack_bf16(x0.x, x0.y);
      wd[1] = pack_bf16(x0.z, x0.w);
      wd[2] = pack_bf16(x1.x, x1.y);
      wd[3] = pack_bf16(x1.z, x1.w);
      const bf16x8 bfrag = __builtin_bit_cast(bf16x8, wd);

      // A fragments (Wt): row = n = n0+i*16+lr, same k. 16B loads, L1-hot
      // (per-kb working set 1.5 KB, shared by all 4 waves of the block).
#pragma unroll
      for (int i = 0; i < 6; ++i) {
        const bf16x8 afrag = *reinterpret_cast<const bf16x8*>(
            Wh + (size_t)(n0 + i * 16 + lr) * 192 + kb * 32 + lg * 8);
        acc[i] = __builtin_amdgcn_mfma_f32_16x16x32_bf16(afrag, bfrag,
                                                         acc[i], 0, 0, 0);
      }
    }

    // store: f32x4, row lr, cols n0+i*16+lg*4 — plain stores, L2 merges.
#pragma unroll
    for (int i = 0; i < 6; ++i)
      *reinterpret_cast<f32x4*>(ob + (size_t)lr * 768 + n0 + i * 16 + lg * 4) =
          acc[i];
  }
}

extern "C" void kernel_launch(void* const* d_in, const int* in_sizes, int n_in,
                              void* d_out, int out_size, void* d_ws, size_t ws_size,
                              hipStream_t stream) {
  const float* z  = (const float*)d_in[0];   // [65536, 768]
  const float* A  = (const float*)d_in[1];   // [6, 192, 4]
  const float* Bm = (const float*)d_in[2];   // [6, 4, 192] == [24][192]
  const float* Zs = (const float*)d_in[3];   // [4, 6]
  const float* Za = (const float*)d_in[4];   // [4, 6]
  float* out = (float*)d_out;                // [65536, 768]
  __hip_bfloat16* Wt = (__hip_bfloat16*)d_ws; // [4][192][192] bf16 = 294,912 B

  dff_setup<<<192, 256, 0, stream>>>(A, Bm, Zs, Za, Wt);
  dff_mfma<<<dim3(1024, 4), 256, 0, stream>>>(z, Wt, out);
}

// Round 10
// 133.150 us; speedup vs baseline: 1.8205x; 1.8205x over previous
//
#include <hip/hip_runtime.h>
#include <hip/hip_bf16.h>

// DIM=768, H=4, D_H=192, R_H=4, N_EXP=6, TOPK=3, BETA=0.5, BATCH=65536
// Routing is batch-independent -> fold softmax/topk/renorm/BETA into c[h][e].
// Tables precomputed in ws as PACKED BF16 PAIRS (u32 = 2 bf16):
//   Acp[h][s][dp] : pair (d=2dp,2dp+1) of c[h][e]*A[e][d][r], s=e*4+r
//                   -> 4 heads x 24 s x 96 dp = 9216 u32          [0..9216)
//   Bp [sp][d]    : pair (s=2sp,2sp+1) of B[s][d], sp=0..11
//                   -> 12 x 192 = 2304 u32                        [9216..11520)
// out[b, h*192+d] = z + sum_s (sum_d' z[d']*Ac[s][d']) * B[s][d]
//
// v10 = r9 with the table-layout bug fixed (r9 sized Acp[h] as 1152 u32; it
// is 2304 -> phase-1 reads ran into the Bp region => absmax 0.164). All
// index math re-derived: lane q owns d = 64j+8q+{0..7}, j=0..2.
//  - bf16 tables: one ds_read_b128 = 8 values -> per-thread LDS reads 144
//    (vs r3's 288; r3 was LDS-pipe bound at 124us).
//  - v_dot2_f32_bf16 (guarded) or exact unpack+fma fallback.
//  - per-thread regs ~50: inside the 64-VGPR envelope the allocator enforces
//    on 256-thd blocks (r2/r4/r8). Residual z re-read in phase 2 (L1-hot).
//  - LDS 18.4 KB/block -> 8 blocks/CU (thread-capped anyway).

typedef float f4 __attribute__((ext_vector_type(4)));
typedef unsigned int u32;
typedef u32 u32x4 __attribute__((ext_vector_type(4)));

// f32 -> bf16 (round half up via +0x8000) packed pair into one u32 (lo=a).
__device__ __forceinline__ u32 pack_bf16(float a, float b) {
  const u32 ua = __builtin_bit_cast(u32, a) + 0x8000u;
  const u32 ub = __builtin_bit_cast(u32, b) + 0x8000u;
  return (ua >> 16) | (ub & 0xFFFF0000u);
}

#if __has_builtin(__builtin_amdgcn_fdot2_f32_bf16)
typedef __bf16 bf16x2 __attribute__((ext_vector_type(2)));
__device__ __forceinline__ float dot2(u32 a, u32 b, float c) {
  return __builtin_amdgcn_fdot2_f32_bf16(__builtin_bit_cast(bf16x2, a),
                                         __builtin_bit_cast(bf16x2, b), c, false);
}
#else
__device__ __forceinline__ float dot2(u32 a, u32 b, float c) {
  const float alo = __builtin_bit_cast(float, a << 16);
  const float ahi = __builtin_bit_cast(float, a & 0xFFFF0000u);
  const float blo = __builtin_bit_cast(float, b << 16);
  const float bhi = __builtin_bit_cast(float, b & 0xFFFF0000u);
  return fmaf(ahi, bhi, fmaf(alo, blo, c));
}
#endif

__global__ void dff_setup(const float* __restrict__ A,
                          const float* __restrict__ Bm,
                          const float* __restrict__ Zs,
                          const float* __restrict__ Za,
                          u32* __restrict__ T) {  // [0..9216)=Acp, [9216..11520)=Bp
  __shared__ float c[4][6];
  const int t = threadIdx.x;
  if (t < 4) {
    const int h = t;
    float cc[6] = {0.f, 0.f, 0.f, 0.f, 0.f, 0.f};
    for (int rt = 0; rt < 2; ++rt) {
      const float* Z = rt ? Za : Zs;
      float zz[6];
      float mx = -1e30f;
      for (int e = 0; e < 6; ++e) { zz[e] = Z[h * 6 + e]; mx = fmaxf(mx, zz[e]); }
      float p[6];
      float sum = 0.f;
      for (int e = 0; e < 6; ++e) { p[e] = expf(zz[e] - mx); sum += p[e]; }
      for (int e = 0; e < 6; ++e) p[e] /= sum;
      // top-3 (ties -> lowest index, matching lax.top_k)
      bool used[6] = {false, false, false, false, false, false};
      float ws = 0.f;
      int sel[3];
      float pv[3];
      for (int k = 0; k < 3; ++k) {
        int best = -1;
        float bv = -1.f;
        for (int e = 0; e < 6; ++e)
          if (!used[e] && p[e] > bv) { bv = p[e]; best = e; }
        used[best] = true;
        sel[k] = best;
        pv[k] = bv;
        ws += bv;
      }
      const float inv = 1.f / (ws + 1e-8f);
      for (int k = 0; k < 3; ++k) cc[sel[k]] += pv[k] * inv;
    }
    for (int e = 0; e < 6; ++e) c[h][e] = 0.5f * cc[e];  // BETA folded in
  }
  __syncthreads();
  for (int i = threadIdx.x; i < 11520; i += blockDim.x) {
    if (i < 9216) {
      // Acp: u32 idx = h*2304 + s*96 + dp ; value pair (d=2dp, 2dp+1)
      const int h = i / 2304;
      const int rem = i % 2304;
      const int s = rem / 96;
      const int dp = rem % 96;
      const int e = s >> 2, r = s & 3;
      const float lo = c[h][e] * A[e * 768 + (2 * dp) * 4 + r];
      const float hi = c[h][e] * A[e * 768 + (2 * dp + 1) * 4 + r];
      T[i] = pack_bf16(lo, hi);
    } else {
      // Bp: u32 idx = 9216 + sp*192 + d ; value pair (s=2sp, 2sp+1)
      const int k = i - 9216;
      const int sp = k / 192;
      const int d = k % 192;
      T[i] = pack_bf16(Bm[(2 * sp) * 192 + d], Bm[(2 * sp + 1) * 192 + d]);
    }
  }
}

__global__ __launch_bounds__(256, 4)
void dff_main(const float* __restrict__ z,
              const u32* __restrict__ T,
              float* __restrict__ out) {
  __shared__ __align__(16) u32 sT[4608];  // [0..2304) Acp[h], [2304..4608) Bp
  u32x4* sT4 = reinterpret_cast<u32x4*>(sT);

  const int t = threadIdx.x;               // 0..255
  const int q = t & 7;                     // eighth within row-group
  const int rl = t >> 3;                   // 0..31 local row
  const int h = blockIdx.y;                // head (block-uniform)
  const int row = blockIdx.x * 32 + rl;    // 2048*32 = 65536 exact
  const float* __restrict__ zp = z + (size_t)row * 768 + h * 192;
  float* __restrict__ op = out + (size_t)row * 768 + h * 192;

  // Issue z loads first so HBM latency overlaps the LDS table fill.
  // Lane's 24 floats = d = 64j+8q+{0..7}, j=0..2; f4-chunk = 16j+2q+half.
  f4 zv[6];
#pragma unroll
  for (int k = 0; k < 6; ++k)
    zv[k] = reinterpret_cast<const f4*>(zp)[16 * (k >> 1) + 2 * q + (k & 1)];

  // Stage tables into LDS: Acp[h] = u32x4 [h*576, h*576+576); Bp at 2304/4.
  {
    const u32x4* __restrict__ Tw = reinterpret_cast<const u32x4*>(T);
    for (int i = t; i < 576; i += 256) {
      sT4[i] = Tw[h * 576 + i];
      sT4[576 + i] = Tw[2304 + i];
    }
  }

  // Pack z to bf16 pairs (zv dead afterwards -> registers reused).
  u32 zpk[12];
#pragma unroll
  for (int j = 0; j < 3; ++j) {
    zpk[4 * j + 0] = pack_bf16(zv[2 * j].x, zv[2 * j].y);
    zpk[4 * j + 1] = pack_bf16(zv[2 * j].z, zv[2 * j].w);
    zpk[4 * j + 2] = pack_bf16(zv[2 * j + 1].x, zv[2 * j + 1].y);
    zpk[4 * j + 3] = pack_bf16(zv[2 * j + 1].z, zv[2 * j + 1].w);
  }
  __syncthreads();

  // phase 1: tmp[s] over lane's 24 d. One b128 per (s,j) = 4 d-pairs.
  // sT4 idx = s*24 + 8j + q  ->  u32 = s*96 + 32j + 4q -> dp = 32j+4q+{0..3}
  // -> d = 64j+8q+{0..7}  (matches zpk). 128B contiguous across q.
  float tmp[24];
#pragma unroll
  for (int s = 0; s < 24; ++s) {
    float acc = 0.f;
#pragma unroll
    for (int j = 0; j < 3; ++j) {
      const u32x4 av = sT4[s * 24 + 8 * j + q];
      acc = dot2(zpk[4 * j + 0], av.x, acc);
      acc = dot2(zpk[4 * j + 1], av.y, acc);
      acc = dot2(zpk[4 * j + 2], av.z, acc);
      acc = dot2(zpk[4 * j + 3], av.w, acc);
    }
    tmp[s] = acc;
  }

  // reduce tmp across the 8-lane group
#pragma unroll
  for (int s = 0; s < 24; ++s) {
    tmp[s] += __shfl_xor(tmp[s], 1, 64);
    tmp[s] += __shfl_xor(tmp[s], 2, 64);
    tmp[s] += __shfl_xor(tmp[s], 4, 64);
  }

  // pack tmp to bf16 s-pairs (tmp dead afterwards).
  u32 tp[12];
#pragma unroll
  for (int i = 0; i < 12; ++i) tp[i] = pack_bf16(tmp[2 * i], tmp[2 * i + 1]);

  // phase 2: out[d] = z[d] + sum_sp dot2(tp[sp], Bp[sp][d]).
  // Bp u32x4 idx = 576 + sp*48 + (8j+q)*2 + {0,1} -> d = 64j+8q+{0..3}/{4..7}.
  // Residual z re-read (same lines as phase 1 -> L1/L2 hot).
#pragma unroll
  for (int j = 0; j < 3; ++j) {
    const int c0 = 16 * j + 2 * q;
    f4 o0 = reinterpret_cast<const f4*>(zp)[c0];
    f4 o1 = reinterpret_cast<const f4*>(zp)[c0 + 1];
#pragma unroll
    for (int sp = 0; sp < 12; ++sp) {
      const int base = 576 + sp * 48 + (8 * j + q) * 2;
      const u32x4 b0 = sT4[base];
      const u32x4 b1 = sT4[base + 1];
      o0.x = dot2(tp[sp], b0.x, o0.x);
      o0.y = dot2(tp[sp], b0.y, o0.y);
      o0.z = dot2(tp[sp], b0.z, o0.z);
      o0.w = dot2(tp[sp], b0.w, o0.w);
      o1.x = dot2(tp[sp], b1.x, o1.x);
      o1.y = dot2(tp[sp], b1.y, o1.y);
      o1.z = dot2(tp[sp], b1.z, o1.z);
      o1.w = dot2(tp[sp], b1.w, o1.w);
    }
    __builtin_nontemporal_store(o0, reinterpret_cast<f4*>(op) + c0);
    __builtin_nontemporal_store(o1, reinterpret_cast<f4*>(op) + c0 + 1);
  }
}

extern "C" void kernel_launch(void* const* d_in, const int* in_sizes, int n_in,
                              void* d_out, int out_size, void* d_ws, size_t ws_size,
                              hipStream_t stream) {
  const float* z  = (const float*)d_in[0];   // [65536, 768]
  const float* A  = (const float*)d_in[1];   // [6, 192, 4]
  const float* Bm = (const float*)d_in[2];   // [6, 4, 192] == [24][192]
  const float* Zs = (const float*)d_in[3];   // [4, 6]
  const float* Za = (const float*)d_in[4];   // [4, 6]
  float* out = (float*)d_out;                // [65536, 768]
  u32* T = (u32*)d_ws;                       // 11520 u32 = 46080 B

  dff_setup<<<1, 256, 0, stream>>>(A, Bm, Zs, Za, T);
  dff_main<<<dim3(2048, 4), 256, 0, stream>>>(z, T, out);
}

// Round 11
// 124.904 us; speedup vs baseline: 1.9407x; 1.0660x over previous
//
#include <hip/hip_runtime.h>
#include <hip/hip_bf16.h>

// DIM=768, H=4, D_H=192, R_H=4, N_EXP=6, TOPK=3, BETA=0.5, BATCH=65536
// Routing is batch-independent -> fold softmax/topk/renorm/BETA into c[h][e].
// Tables in ws as PACKED BF16 PAIRS (u32 = 2 bf16):
//   Acp[h][s][dp] : pair (d=2dp,2dp+1) of c[h][e]*A[e][d][r], s=e*4+r
//                   -> 4 x 24 x 96 = 9216 u32                     [0..9216)
//   Bp [sp][d]    : pair (s=2sp,2sp+1) of B[s][d], sp=0..11
//                   -> 12 x 192 = 2304 u32                        [9216..11520)
// out[b, h*192+d] = z + sum_s (sum_d' z[d']*Ac[s][d']) * B[s][d]
//
// v11 = r10 (133us, LDS-pipe bound: 4.72M ds_read_b128 ~= 92us) with:
//  - 2-ROW BATCHING: thread serves rows (row0, row0+32); every table b128
//    feeds both rows -> table LDS instrs halve (92->46us).
//  - s-CHUNKED tmp (live tmp[2][4], tp accumulates) keeps reg peak ~60,
//    inside the 64-VGPR envelope the allocator enforces on 256-thd blocks.
//  - reduce via DPP quad_perm adds (xor1/xor2, VALU pipe) + ONE ds_swizzle
//    (xor4) -> reduce LDS ops cut 3x.
//  - PLAIN stores (r10's NT stores at 32B lane-stride = partial lines ->
//    +74MB write amplification; r8 plain stores wrote exactly 196,608 KB).
// Index math identical to r10 (proven): lane q owns d = 64j+8q+{0..7}.

typedef float f4 __attribute__((ext_vector_type(4)));
typedef unsigned int u32;
typedef u32 u32x4 __attribute__((ext_vector_type(4)));

// f32 -> bf16 (round half up via +0x8000) packed pair into one u32 (lo=a).
__device__ __forceinline__ u32 pack_bf16(float a, float b) {
  const u32 ua = __builtin_bit_cast(u32, a) + 0x8000u;
  const u32 ub = __builtin_bit_cast(u32, b) + 0x8000u;
  return (ua >> 16) | (ub & 0xFFFF0000u);
}

#if __has_builtin(__builtin_amdgcn_fdot2_f32_bf16)
typedef __bf16 bf16x2 __attribute__((ext_vector_type(2)));
__device__ __forceinline__ float dot2(u32 a, u32 b, float c) {
  return __builtin_amdgcn_fdot2_f32_bf16(__builtin_bit_cast(bf16x2, a),
                                         __builtin_bit_cast(bf16x2, b), c, false);
}
#else
__device__ __forceinline__ float dot2(u32 a, u32 b, float c) {
  const float alo = __builtin_bit_cast(float, a << 16);
  const float ahi = __builtin_bit_cast(float, a & 0xFFFF0000u);
  const float blo = __builtin_bit_cast(float, b << 16);
  const float bhi = __builtin_bit_cast(float, b & 0xFFFF0000u);
  return fmaf(ahi, bhi, fmaf(alo, blo, c));
}
#endif

// Butterfly sum over lane^1, lane^2 (DPP quad_perm, VALU pipe) and lane^4
// (ds_swizzle BitMode 0x101F). All lanes end with the 8-lane group sum.
__device__ __forceinline__ float qsum8(float x) {
  int xi = __builtin_bit_cast(int, x);
  // xor1: quad_perm [1,0,3,2] = 0xB1
  x += __builtin_bit_cast(float,
        __builtin_amdgcn_update_dpp(0, xi, 0xB1, 0xF, 0xF, true));
  xi = __builtin_bit_cast(int, x);
  // xor2: quad_perm [2,3,0,1] = 0x4E
  x += __builtin_bit_cast(float,
        __builtin_amdgcn_update_dpp(0, xi, 0x4E, 0xF, 0xF, true));
  xi = __builtin_bit_cast(int, x);
  // xor4: ds_swizzle, offset = (4<<10)|0x1F
  x += __builtin_bit_cast(float, __builtin_amdgcn_ds_swizzle(xi, 0x101F));
  return x;
}

__global__ void dff_setup(const float* __restrict__ A,
                          const float* __restrict__ Bm,
                          const float* __restrict__ Zs,
                          const float* __restrict__ Za,
                          u32* __restrict__ T) {  // [0..9216)=Acp, [9216..11520)=Bp
  __shared__ float c[4][6];
  const int t = threadIdx.x;
  if (t < 4) {
    const int h = t;
    float cc[6] = {0.f, 0.f, 0.f, 0.f, 0.f, 0.f};
    for (int rt = 0; rt < 2; ++rt) {
      const float* Z = rt ? Za : Zs;
      float zz[6];
      float mx = -1e30f;
      for (int e = 0; e < 6; ++e) { zz[e] = Z[h * 6 + e]; mx = fmaxf(mx, zz[e]); }
      float p[6];
      float sum = 0.f;
      for (int e = 0; e < 6; ++e) { p[e] = expf(zz[e] - mx); sum += p[e]; }
      for (int e = 0; e < 6; ++e) p[e] /= sum;
      // top-3 (ties -> lowest index, matching lax.top_k)
      bool used[6] = {false, false, false, false, false, false};
      float ws = 0.f;
      int sel[3];
      float pv[3];
      for (int k = 0; k < 3; ++k) {
        int best = -1;
        float bv = -1.f;
        for (int e = 0; e < 6; ++e)
          if (!used[e] && p[e] > bv) { bv = p[e]; best = e; }
        used[best] = true;
        sel[k] = best;
        pv[k] = bv;
        ws += bv;
      }
      const float inv = 1.f / (ws + 1e-8f);
      for (int k = 0; k < 3; ++k) cc[sel[k]] += pv[k] * inv;
    }
    for (int e = 0; e < 6; ++e) c[h][e] = 0.5f * cc[e];  // BETA folded in
  }
  __syncthreads();
  for (int i = threadIdx.x; i < 11520; i += blockDim.x) {
    if (i < 9216) {
      // Acp: u32 idx = h*2304 + s*96 + dp ; value pair (d=2dp, 2dp+1)
      const int h = i / 2304;
      const int rem = i % 2304;
      const int s = rem / 96;
      const int dp = rem % 96;
      const int e = s >> 2, r = s & 3;
      const float lo = c[h][e] * A[e * 768 + (2 * dp) * 4 + r];
      const float hi = c[h][e] * A[e * 768 + (2 * dp + 1) * 4 + r];
      T[i] = pack_bf16(lo, hi);
    } else {
      // Bp: u32 idx = 9216 + sp*192 + d ; value pair (s=2sp, 2sp+1)
      const int k = i - 9216;
      const int sp = k / 192;
      const int d = k % 192;
      T[i] = pack_bf16(Bm[(2 * sp) * 192 + d], Bm[(2 * sp + 1) * 192 + d]);
    }
  }
}

__global__ __launch_bounds__(256, 4)
void dff_main(const float* __restrict__ z,
              const u32* __restrict__ T,
              float* __restrict__ out) {
  __shared__ __align__(16) u32 sT[4608];  // [0..2304) Acp[h], [2304..4608) Bp
  u32x4* sT4 = reinterpret_cast<u32x4*>(sT);

  const int t = threadIdx.x;               // 0..255
  const int q = t & 7;                     // eighth within row-group (lane&7)
  const int rl = t >> 3;                   // 0..31 row slot
  const int h = blockIdx.y;                // head (block-uniform)
  const int row0 = blockIdx.x * 64 + rl;   // rows row0, row0+32 (1024*64=65536)
  const float* __restrict__ zp0 = z + (size_t)row0 * 768 + h * 192;
  const float* __restrict__ zp1 = zp0 + 32 * 768;
  float* __restrict__ op0 = out + (size_t)row0 * 768 + h * 192;
  float* __restrict__ op1 = op0 + 32 * 768;

  // Issue z loads first so HBM latency overlaps the LDS table fill.
  // Lane's 24 d per row: d = 64j+8q+{0..7}; f4-chunk = 16j+2q+half.
  f4 zv0[6], zv1[6];
#pragma unroll
  for (int k = 0; k < 6; ++k) {
    const int ci = 16 * (k >> 1) + 2 * q + (k & 1);
    zv0[k] = reinterpret_cast<const f4*>(zp0)[ci];
    zv1[k] = reinterpret_cast<const f4*>(zp1)[ci];
  }

  // Stage tables into LDS: Acp[h] u32x4 [0,576); Bp [576,1152).
  {
    const u32x4* __restrict__ Tw = reinterpret_cast<const u32x4*>(T);
    for (int i = t; i < 576; i += 256) {
      sT4[i] = Tw[h * 576 + i];
      sT4[576 + i] = Tw[2304 + i];
    }
  }

  // Pack z to bf16 pairs (zv dies -> regs reused).
  u32 zpk0[12], zpk1[12];
#pragma unroll
  for (int j = 0; j < 3; ++j) {
    zpk0[4 * j + 0] = pack_bf16(zv0[2 * j].x, zv0[2 * j].y);
    zpk0[4 * j + 1] = pack_bf16(zv0[2 * j].z, zv0[2 * j].w);
    zpk0[4 * j + 2] = pack_bf16(zv0[2 * j + 1].x, zv0[2 * j + 1].y);
    zpk0[4 * j + 3] = pack_bf16(zv0[2 * j + 1].z, zv0[2 * j + 1].w);
    zpk1[4 * j + 0] = pack_bf16(zv1[2 * j].x, zv1[2 * j].y);
    zpk1[4 * j + 1] = pack_bf16(zv1[2 * j].z, zv1[2 * j].w);
    zpk1[4 * j + 2] = pack_bf16(zv1[2 * j + 1].x, zv1[2 * j + 1].y);
    zpk1[4 * j + 3] = pack_bf16(zv1[2 * j + 1].z, zv1[2 * j + 1].w);
  }
  __syncthreads();

  // phase 1, s-chunked (6 chunks of 4 s): tmp live = 2x4; each table b128
  // feeds BOTH rows (8 dot2 per read). sT4 idx s*24+8j+q -> d=64j+8q+{0..7}.
  u32 tp0[12], tp1[12];
#pragma unroll
  for (int c = 0; c < 6; ++c) {
    float tmp0[4], tmp1[4];
#pragma unroll
    for (int u = 0; u < 4; ++u) {
      const int s = 4 * c + u;
      float a0 = 0.f, a1 = 0.f;
#pragma unroll
      for (int j = 0; j < 3; ++j) {
        const u32x4 av = sT4[s * 24 + 8 * j + q];
        a0 = dot2(zpk0[4 * j + 0], av.x, a0);
        a0 = dot2(zpk0[4 * j + 1], av.y, a0);
        a0 = dot2(zpk0[4 * j + 2], av.z, a0);
        a0 = dot2(zpk0[4 * j + 3], av.w, a0);
        a1 = dot2(zpk1[4 * j + 0], av.x, a1);
        a1 = dot2(zpk1[4 * j + 1], av.y, a1);
        a1 = dot2(zpk1[4 * j + 2], av.z, a1);
        a1 = dot2(zpk1[4 * j + 3], av.w, a1);
      }
      tmp0[u] = a0;
      tmp1[u] = a1;
    }
    // 8-lane group sum (q-octet): DPP xor1/xor2 + ds_swizzle xor4.
#pragma unroll
    for (int u = 0; u < 4; ++u) {
      tmp0[u] = qsum8(tmp0[u]);
      tmp1[u] = qsum8(tmp1[u]);
    }
    tp0[2 * c + 0] = pack_bf16(tmp0[0], tmp0[1]);
    tp0[2 * c + 1] = pack_bf16(tmp0[2], tmp0[3]);
    tp1[2 * c + 0] = pack_bf16(tmp1[0], tmp1[1]);
    tp1[2 * c + 1] = pack_bf16(tmp1[2], tmp1[3]);
  }

  // phase 2: out[d] = z[d] + sum_sp dot2(tp[sp], Bp[sp][d]); each b128 feeds
  // both rows. Residual z re-read (L1/L2-hot). PLAIN stores -> L2 merges.
#pragma unroll
  for (int j = 0; j < 3; ++j) {
    const int c0 = 16 * j + 2 * q;
    f4 o00 = reinterpret_cast<const f4*>(zp0)[c0];
    f4 o01 = reinterpret_cast<const f4*>(zp0)[c0 + 1];
    f4 o10 = reinterpret_cast<const f4*>(zp1)[c0];
    f4 o11 = reinterpret_cast<const f4*>(zp1)[c0 + 1];
#pragma unroll
    for (int sp = 0; sp < 12; ++sp) {
      const int base = 576 + sp * 48 + (8 * j + q) * 2;
      const u32x4 b0 = sT4[base];
      const u32x4 b1 = sT4[base + 1];
      o00.x = dot2(tp0[sp], b0.x, o00.x);
      o00.y = dot2(tp0[sp], b0.y, o00.y);
      o00.z = dot2(tp0[sp], b0.z, o00.z);
      o00.w = dot2(tp0[sp], b0.w, o00.w);
      o01.x = dot2(tp0[sp], b1.x, o01.x);
      o01.y = dot2(tp0[sp], b1.y, o01.y);
      o01.z = dot2(tp0[sp], b1.z, o01.z);
      o01.w = dot2(tp0[sp], b1.w, o01.w);
      o10.x = dot2(tp1[sp], b0.x, o10.x);
      o10.y = dot2(tp1[sp], b0.y, o10.y);
      o10.z = dot2(tp1[sp], b0.z, o10.z);
      o10.w = dot2(tp1[sp], b0.w, o10.w);
      o11.x = dot2(tp1[sp], b1.x, o11.x);
      o11.y = dot2(tp1[sp], b1.y, o11.y);
      o11.z = dot2(tp1[sp], b1.z, o11.z);
      o11.w = dot2(tp1[sp], b1.w, o11.w);
    }
    reinterpret_cast<f4*>(op0)[c0] = o00;
    reinterpret_cast<f4*>(op0)[c0 + 1] = o01;
    reinterpret_cast<f4*>(op1)[c0] = o10;
    reinterpret_cast<f4*>(op1)[c0 + 1] = o11;
  }
}

extern "C" void kernel_launch(void* const* d_in, const int* in_sizes, int n_in,
                              void* d_out, int out_size, void* d_ws, size_t ws_size,
                              hipStream_t stream) {
  const float* z  = (const float*)d_in[0];   // [65536, 768]
  const float* A  = (const float*)d_in[1];   // [6, 192, 4]
  const float* Bm = (const float*)d_in[2];   // [6, 4, 192] == [24][192]
  const float* Zs = (const float*)d_in[3];   // [4, 6]
  const float* Za = (const float*)d_in[4];   // [4, 6]
  float* out = (float*)d_out;                // [65536, 768]
  u32* T = (u32*)d_ws;                       // 11520 u32 = 46080 B

  dff_setup<<<1, 256, 0, stream>>>(A, Bm, Zs, Za, T);
  dff_main<<<dim3(1024, 4), 256, 0, stream>>>(z, T, out);
}